// Round 12
// baseline (403.413 us; speedup 1.0000x reference)
//
#include <hip/hip_runtime.h>
#include <hip/hip_bf16.h>
#include <stdint.h>

typedef __bf16 bf16_t;
typedef __attribute__((ext_vector_type(4))) float floatx4;
typedef __attribute__((ext_vector_type(8))) __bf16 bf16x8;
typedef __attribute__((ext_vector_type(4))) __bf16 bf16x4;

#define MFMA16(a, b, c) __builtin_amdgcn_mfma_f32_16x16x32_bf16(a, b, c, 0, 0, 0)

// async global->LDS, 16B per lane. LDS dest must be wave-uniform base (+lane*16 by HW).
#define GLOAD_LDS16(gsrc, ldst)                                                          \
  __builtin_amdgcn_global_load_lds((const __attribute__((address_space(1))) void*)(gsrc),\
                                   (__attribute__((address_space(3))) void*)(ldst),      \
                                   16, 0, 0)

#define BATCH 16
#define SEQ   577
#define EMB   1024
#define NH    16
#define HD    64
#define SPAD  640            // padded seq for attention buffers
#define MROWS (BATCH * SEQ)  // 9232
#define MPAD  9344           // 73 * 128

// exp(s/8) = 2^(s * log2(e)/8)
#define EXP_C 0.1803368801111404f

// ---------------- workspace layout (bytes) ----------------
#define OFF_H  0ULL                      // [MPAD][EMB] bf16      19,136,512
#define OFF_WQ 19136512ULL               // [EMB][EMB] bf16        2,097,152
#define OFF_WK 21233664ULL
#define OFF_WV 23330816ULL
#define OFF_WO 25427968ULL
#define OFF_Q  27525120ULL               // [B*H][SPAD][HD] bf16  20,971,520
#define OFF_K  48496640ULL
#define OFF_VT 69468160ULL               // [B*H][HD][SPAD] bf16 (transposed V)
#define OFF_AO 90439680ULL               // [MPAD][EMB] bf16      19,136,512

// ---------------- fp32 -> bf16 cast ----------------
__global__ __launch_bounds__(256) void k_cast(
    const float4* __restrict__ hs, const float4* __restrict__ wq,
    const float4* __restrict__ wk, const float4* __restrict__ wv,
    const float4* __restrict__ wo, bf16x4* __restrict__ hb, bf16x4* __restrict__ wqb,
    bf16x4* __restrict__ wkb, bf16x4* __restrict__ wvb, bf16x4* __restrict__ wob) {
  int idx = blockIdx.x * 256 + threadIdx.x;
  const int H4 = MROWS * EMB / 4;  // 2363392
  const int W4 = EMB * EMB / 4;    // 262144
  const float4* src;
  bf16x4* dst;
  int i;
  if (idx < H4) {
    src = hs; dst = hb; i = idx;
  } else {
    int r = idx - H4;
    int w = r / W4;
    if (w >= 4) return;
    i = r - w * W4;
    src = (w == 0) ? wq : (w == 1) ? wk : (w == 2) ? wv : wo;
    dst = (w == 0) ? wqb : (w == 1) ? wkb : (w == 2) ? wvb : wob;
  }
  float4 v = src[i];
  bf16x4 o;
  o.x = (bf16_t)v.x; o.y = (bf16_t)v.y; o.z = (bf16_t)v.z; o.w = (bf16_t)v.w;
  dst[i] = o;
}

// ---------------- fused QKV projection + RoPE (z-fused, n-tile=64=one head)
// R9-proven: 2-phase dbuf + source-side XOR swizzle (8-way -> 2-way on
// ds_read_b128). Untouched this round.
__global__ __launch_bounds__(256, 3) void k_qkv(const bf16_t* __restrict__ A,
                                                const bf16_t* __restrict__ Wq,
                                                const bf16_t* __restrict__ Wk,
                                                const bf16_t* __restrict__ Wv,
                                                const float* __restrict__ bq,
                                                const float* __restrict__ bk,
                                                const float* __restrict__ bv,
                                                bf16_t* __restrict__ qb,
                                                bf16_t* __restrict__ kb,
                                                bf16_t* __restrict__ vtb) {
  // per buffer: As 128x32 (4096 el) | Bs 3x64x32 (6144 el) = 20480 B; x2 = 40960 B -> 4 blocks/CU
  __shared__ __align__(16) bf16_t smem[2 * 10240];
  const int hh = blockIdx.x;           // head == n-tile
  const int n0 = hh * 64;
  const int m0 = blockIdx.y * 128;
  const int t = threadIdx.x;
  const int wid = t >> 6, lane = t & 63, quad = lane >> 4, c = lane & 15;

  // staging: row = t>>2; source slot XOR-swizzled so linear LDS dest ends up
  // holding LDS[row][slot] = G[row][slot ^ ((row>>1)&3)]
  const int srow0 = t >> 2;                              // rows 0..63
  const int srow1 = 64 + srow0;                          // rows 64..127
  const int soff = (((t & 3) ^ ((t >> 3) & 3)) * 8);     // swizzled 16B slot (elems)

#define QKV_STAGE(buf, k0)                                                                  \
  {                                                                                         \
    bf16_t* As_ = smem + (buf) * 10240;                                                     \
    bf16_t* Bs_ = As_ + 4096;                                                               \
    GLOAD_LDS16(A + (size_t)(m0 + srow0) * EMB + (k0) + soff, (char*)As_ + (wid * 64) * 16);\
    GLOAD_LDS16(A + (size_t)(m0 + srow1) * EMB + (k0) + soff,                               \
                (char*)As_ + (256 + wid * 64) * 16);                                        \
    GLOAD_LDS16(Wq + (size_t)(n0 + srow0) * EMB + (k0) + soff, (char*)Bs_ + (wid * 64) * 16);\
    GLOAD_LDS16(Wk + (size_t)(n0 + srow0) * EMB + (k0) + soff,                              \
                (char*)Bs_ + 4096 + (wid * 64) * 16);                                       \
    GLOAD_LDS16(Wv + (size_t)(n0 + srow0) * EMB + (k0) + soff,                              \
                (char*)Bs_ + 8192 + (wid * 64) * 16);                                       \
  }

  floatx4 acc[3][2][4];
#pragma unroll
  for (int z = 0; z < 3; z++)
#pragma unroll
    for (int i = 0; i < 2; i++)
#pragma unroll
      for (int j = 0; j < 4; j++) {
        floatx4 zz = {0.f, 0.f, 0.f, 0.f};
        acc[z][i][j] = zz;
      }

  QKV_STAGE(0, 0);
  __syncthreads();  // buf0 staged (compiler drains vmcnt here)
  int cur = 0;
  for (int kt = 0; kt < 32; kt++) {
    if (kt < 31) QKV_STAGE(cur ^ 1, (kt + 1) * 32);  // async; flies under compute below
    const bf16_t* Asc = smem + cur * 10240;
    const bf16_t* Bsc = Asc + 4096;
    bf16x8 af[2];
#pragma unroll
    for (int mi = 0; mi < 2; mi++) {
      int row = wid * 32 + mi * 16 + c;
      af[mi] = *(const bf16x8*)(Asc + row * 32 + (quad * 8 ^ (((row >> 1) & 3) << 3)));
    }
#pragma unroll
    for (int z = 0; z < 3; z++) {
      bf16x8 bfr[4];
#pragma unroll
      for (int ni = 0; ni < 4; ni++) {
        int row = ni * 16 + c;
        bfr[ni] = *(const bf16x8*)(Bsc + z * 2048 + row * 32 + (quad * 8 ^ (((row >> 1) & 3) << 3)));
      }
#pragma unroll
      for (int mi = 0; mi < 2; mi++)
#pragma unroll
        for (int ni = 0; ni < 4; ni++) acc[z][mi][ni] = MFMA16(af[mi], bfr[ni], acc[z][mi][ni]);
    }
    __syncthreads();  // drains next-tile loads (already covered) + read-done for buf[cur]
    cur ^= 1;
  }
#undef QKV_STAGE

  // inv_freq[c] = 10000^(-c/16) = 2^(-c*log2(10000)/16)
  const float invf = exp2f(-(float)c * 0.8304820237218405f);

  for (int z = 0; z < 3; z++) {
    const float* bias = (z == 0) ? bq : (z == 1) ? bk : bv;
    float bias_v[4];
#pragma unroll
    for (int ni = 0; ni < 4; ni++) bias_v[ni] = bias[n0 + ni * 16 + c];
#pragma unroll
    for (int mi = 0; mi < 2; mi++) {
#pragma unroll
      for (int r = 0; r < 4; r++) {
        int m = m0 + wid * 32 + mi * 16 + quad * 4 + r;
        if (m >= MROWS) continue;
        int bb = m / SEQ;
        int s = m - bb * SEQ;
        if (z < 2) {
          float ch = 1.f, sh = 0.f, cw = 1.f, sw = 0.f;
          if (s > 0) {
            int p = s - 1;
            int hp = p / 24, wp2 = p - (p / 24) * 24;
            __sincosf((float)hp * invf, &sh, &ch);
            __sincosf((float)wp2 * invf, &sw, &cw);
          }
          bf16_t* dst = (z == 0) ? qb : kb;
          size_t rowoff = ((size_t)(bb * NH + hh) * SPAD + s) * HD;
#pragma unroll
          for (int ni = 0; ni < 4; ni++) {
            float val = acc[z][mi][ni][r] + bias_v[ni];
            float part = acc[z][mi][ni ^ 2][r] + bias_v[ni ^ 2];
            float rot = (ni < 2) ? -part : part;
            float cs = (ni < 2) ? ch : cw;
            float sn = (ni < 2) ? sh : sw;
            dst[rowoff + ni * 16 + c] = (bf16_t)(val * cs + rot * sn);
          }
        } else {
          size_t base = (size_t)(bb * NH + hh) * HD;
#pragma unroll
          for (int ni = 0; ni < 4; ni++) {
            float val = acc[z][mi][ni][r] + bias_v[ni];
            int d = ni * 16 + c;
            vtb[(base + d) * SPAD + s] = (bf16_t)val;  // transposed store [d][s]
          }
        }
      }
    }
  }
}

// ---------------- flash attention ----------------
// R10-proven geometry: MI=3, grid (16,16,3) = 768 blocks @ 3/CU, single pass.
// R11 LESSON (measured): cutting 16 redundant V-reads dropped conflicts
// 4.5M->2.7M but dur was FLAT -> LDS-pipe throughput is NOT binding. With
// MfmaUtil 9 / VALU 29 / HBM 22 / LDS non-binding, the remaining explanation
// is LOCKSTEP LATENCY: 2 barriers/kt force all 12 waves/CU through serial
// phases with only 3 waves/SIMD of cover.
// R12: double-buffered K/V LDS (2x9KB + Ps 9KB = 46080 B; 3 blocks = 141 KB
// <= 160, residency unchanged) -> write tile kt+1 to buf^1 while computing
// tile kt from buf; ONE barrier per kt. buf^1's last readers finished at the
// previous barrier; all buf^1 writes precede this barrier -> safe. Waves can
// drift a phase instead of marching in lockstep. Inner loop = R10 verbatim.
#define PSTR 72  // P round-trip stride: breaks 128B bank aliasing
#define OSTR 66  // O-transpose stride
#define MI   3   // m-tiles per wave (48 rows)
__global__ __launch_bounds__(256, 3) void k_attn(const bf16_t* __restrict__ qb,
                                                 const bf16_t* __restrict__ kb,
                                                 const bf16_t* __restrict__ vtb,
                                                 bf16_t* __restrict__ ao) {
  // layout: Ks[2] @ 0 / 4608, Vs[2] @ 9216 / 13824, Ps @ 18432 (4*1152)
  __shared__ __align__(16) bf16_t smem[23040];  // 46080 B
  bf16_t* Ps = smem + 18432;
  const int t = threadIdx.x, wid = t >> 6, lane = t & 63, quad = lane >> 4, c = lane & 15;
  const int hh = blockIdx.x, bb = blockIdx.y, qt = blockIdx.z;
  const size_t bh = (size_t)bb * NH + hh;
  const bf16_t* qall = qb + bh * SPAD * HD;
  const bf16_t* qbase = qall + (size_t)qt * 192 * HD;
  const bf16_t* kbase = kb + bh * SPAD * HD;
  const bf16_t* vbase = vtb + bh * HD * SPAD;
  bf16_t* Pw = Ps + wid * 1152;

  // Q fragments direct from global. Max row = 2*192 + 3*48 + 2*16 + 15 = 575:
  // all reads valid, no pad/poison exposure on the Q side.
  bf16x8 aq[MI][2];
#pragma unroll
  for (int mi = 0; mi < MI; mi++)
#pragma unroll
    for (int h = 0; h < 2; h++)
      aq[mi][h] = *(const bf16x8*)(qbase + (size_t)(wid * 48 + mi * 16 + c) * HD + h * 32 + quad * 8);

  // staging addresses (fixed per thread)
  const int srow = (t * 2) >> 3, ssoff = ((t * 2) & 7) * 8;  // = row ci>>3, off (ci&7)*8 pattern below

  // prologue: tile 0 -> regs -> buf0; then tile 1 -> regs
  uint4 kr[2], vr[2];
#pragma unroll
  for (int j = 0; j < 2; j++) {
    int ci = j * 256 + t;
    int row = ci >> 3, off = (ci & 7) * 8;
    kr[j] = *(const uint4*)(kbase + (size_t)row * HD + off);
    vr[j] = *(const uint4*)(vbase + (size_t)row * SPAD + off);
  }
#pragma unroll
  for (int j = 0; j < 2; j++) {
    int ci = j * 256 + t;
    int row = ci >> 3, off = (ci & 7) * 8;
    *(uint4*)((char*)(smem) + (row * PSTR + off) * 2) = kr[j];
    *(uint4*)((char*)(smem + 9216) + (row * PSTR + off) * 2) = vr[j];
  }
#pragma unroll
  for (int j = 0; j < 2; j++) {
    int ci = j * 256 + t;
    int row = ci >> 3, off = (ci & 7) * 8;
    kr[j] = *(const uint4*)(kbase + (size_t)(64 + row) * HD + off);
    vr[j] = *(const uint4*)(vbase + (size_t)row * SPAD + 64 + off);
  }
  __syncthreads();  // buf0 visible (lgkm drained); tile-1 loads in flight

  floatx4 acc_o[MI][4];
  float lsum[MI][4];
#pragma unroll
  for (int mi = 0; mi < MI; mi++) {
    floatx4 z = {0.f, 0.f, 0.f, 0.f};
#pragma unroll
    for (int nd = 0; nd < 4; nd++) acc_o[mi][nd] = z;
#pragma unroll
    for (int r = 0; r < 4; r++) lsum[mi][r] = 0.f;
  }

  int cur = 0;
  for (int kt = 0; kt < 9; kt++) {  // 9*64 = 576 keys exactly; key 576 in epilogue
    const bf16_t* Ksc = smem + cur * 4608;
    const bf16_t* Vsc = smem + 9216 + cur * 4608;
    // write tile kt+1 (in kr/vr) to the other buffer; its last readers
    // finished at the previous barrier.
    if (kt < 8) {
      bf16_t* Ksn = smem + (cur ^ 1) * 4608;
      bf16_t* Vsn = smem + 9216 + (cur ^ 1) * 4608;
#pragma unroll
      for (int j = 0; j < 2; j++) {
        int ci = j * 256 + t;
        int row = ci >> 3, off = (ci & 7) * 8;
        *(uint4*)((char*)Ksn + (row * PSTR + off) * 2) = kr[j];
        *(uint4*)((char*)Vsn + (row * PSTR + off) * 2) = vr[j];
      }
    }
    if (kt < 7) {  // prefetch tile kt+2; overlaps the compute below
#pragma unroll
      for (int j = 0; j < 2; j++) {
        int ci = j * 256 + t;
        int row = ci >> 3, off = (ci & 7) * 8;
        kr[j] = *(const uint4*)(kbase + (size_t)((kt + 2) * 64 + row) * HD + off);
        vr[j] = *(const uint4*)(vbase + (size_t)row * SPAD + (kt + 2) * 64 + off);
      }
    }

    // QK^T: 24 MFMA (K fragments shared across all 3 mi)
    floatx4 sc[MI][4];
#pragma unroll
    for (int ni = 0; ni < 4; ni++) {
      bf16x8 k0 = *(const bf16x8*)(Ksc + (ni * 16 + c) * PSTR + quad * 8);
      bf16x8 k1 = *(const bf16x8*)(Ksc + (ni * 16 + c) * PSTR + 32 + quad * 8);
#pragma unroll
      for (int mi = 0; mi < MI; mi++) {
        floatx4 zz = {0.f, 0.f, 0.f, 0.f};
        zz = MFMA16(aq[mi][0], k0, zz);
        zz = MFMA16(aq[mi][1], k1, zz);
        sc[mi][ni] = zz;
      }
    }

    // per-mi: p = exp(s/8) -> 16-row LDS region (C-layout -> A-layout) -> PV.
    // 16-row Pw reused across mi (same-wave DS ordering); l as scalar partials.
#pragma unroll
    for (int mi = 0; mi < MI; mi++) {
#pragma unroll
      for (int ni = 0; ni < 4; ni++)
#pragma unroll
        for (int r = 0; r < 4; r++) {
          float p = exp2f(sc[mi][ni][r] * EXP_C);
          lsum[mi][r] += p;
          Pw[(quad * 4 + r) * PSTR + ni * 16 + c] = (bf16_t)p;
        }
      // same-wave LDS round trip: no barrier needed
      bf16x8 pa0 = *(const bf16x8*)(Pw + c * PSTR + quad * 8);
      bf16x8 pa1 = *(const bf16x8*)(Pw + c * PSTR + 32 + quad * 8);
      // PV: 8 MFMA
#pragma unroll
      for (int nd = 0; nd < 4; nd++) {
        bf16x8 v0 = *(const bf16x8*)(Vsc + (nd * 16 + c) * PSTR + quad * 8);
        bf16x8 v1 = *(const bf16x8*)(Vsc + (nd * 16 + c) * PSTR + 32 + quad * 8);
        acc_o[mi][nd] = MFMA16(pa0, v0, acc_o[mi][nd]);
        acc_o[mi][nd] = MFMA16(pa1, v1, acc_o[mi][nd]);
      }
    }

    __syncthreads();  // tile kt+1 visible; all waves done with buf[cur]
    cur ^= 1;
  }

  // ---- epilogue: key 576 for query rows 0..575 ----
  {
    bf16x8 klast[2];
#pragma unroll
    for (int h = 0; h < 2; h++) {
      bf16x8 kk;
#pragma unroll
      for (int i = 0; i < 8; i++) kk[i] = (bf16_t)0.0f;
      if (c == 0) kk = *(const bf16x8*)(kbase + (size_t)576 * HD + h * 32 + quad * 8);
      klast[h] = kk;
    }
    float vlast[4];
#pragma unroll
    for (int nd = 0; nd < 4; nd++)
      vlast[nd] = (float)vbase[(size_t)(nd * 16 + c) * SPAD + 576];
#pragma unroll
    for (int mi = 0; mi < MI; mi++) {
      floatx4 zz = {0.f, 0.f, 0.f, 0.f};
      zz = MFMA16(aq[mi][0], klast[0], zz);
      zz = MFMA16(aq[mi][1], klast[1], zz);  // D col 0 (lanes c==0) = scores
#pragma unroll
      for (int r = 0; r < 4; r++) {
        float p = exp2f(zz[r] * EXP_C);
        p = __shfl(p, quad * 16, 64);  // broadcast score row from this quad's c==0 lane
#pragma unroll
        for (int nd = 0; nd < 4; nd++) acc_o[mi][nd][r] += p * vlast[nd];
        if (c == 0) lsum[mi][r] += p;  // count once per row (partials reduce over c later)
      }
    }
  }

  // ---- row-sum finalize: reduce per-lane partials over the 16 c-lanes ----
#pragma unroll
  for (int mi = 0; mi < MI; mi++)
#pragma unroll
    for (int r = 0; r < 4; r++) {
      float l = lsum[mi][r];
      l += __shfl_xor(l, 1, 64);
      l += __shfl_xor(l, 2, 64);
      l += __shfl_xor(l, 4, 64);
      l += __shfl_xor(l, 8, 64);
      lsum[mi][r] = l;  // all lanes in the quad-group now hold the row sum
    }

  // ---- coalesced O-store: per-mi 16-row transpose chunks through Pw (dead now),
  // then full 128B-row dwordx4 stores. Same-wave DS ordering: no barrier.
  {
    const int rsub = lane >> 3, c8 = lane & 7;  // 8 rows/instr, 16B per lane
#pragma unroll
    for (int mi = 0; mi < MI; mi++) {
#pragma unroll
      for (int r = 0; r < 4; r++) {
        float inv_l = 1.f / lsum[mi][r];
        int row = quad * 4 + r;  // row within this 16-row chunk
#pragma unroll
        for (int nd = 0; nd < 4; nd++)
          Pw[row * OSTR + nd * 16 + c] = (bf16_t)(acc_o[mi][nd][r] * inv_l);
      }
#pragma unroll
      for (int j = 0; j < 2; j++) {
        int row = j * 8 + rsub;  // 0..15 within chunk
        bf16x8 ov = *(const bf16x8*)(Pw + row * OSTR + c8 * 8);
        int q = qt * 192 + wid * 48 + mi * 16 + row;  // <= 575, always valid
        if (q < SEQ) {
          size_t mrow = (size_t)bb * SEQ + q;
          *(bf16x8*)(ao + mrow * EMB + hh * HD + c8 * 8) = ov;
        }
      }
    }
  }

  // ---- tail: query row 576 (VALU path, qt==2 blocks only; K/V are L2-hot) ----
  if (qt == 2) {
    float* Pt = (float*)smem;          // 577 floats (2.3 KB) in dead Ks region
    float* Ot = Pt + 584;              // 4*64 floats
    __syncthreads();                   // all waves past their last Ks reads
    // phase 1: scores for keys j = t, t+256, t+512
    bf16x8 qv8[8];
    const bf16_t* q576 = qall + (size_t)576 * HD;
#pragma unroll
    for (int ch = 0; ch < 8; ch++) qv8[ch] = *(const bf16x8*)(q576 + ch * 8);
#pragma unroll
    for (int rep = 0; rep < 3; rep++) {
      int j = t + rep * 256;
      if (j < SEQ) {
        const bf16_t* krow = kbase + (size_t)j * HD;
        float s = 0.f;
#pragma unroll
        for (int ch = 0; ch < 8; ch++) {
          bf16x8 kx = *(const bf16x8*)(krow + ch * 8);
#pragma unroll
          for (int e = 0; e < 8; e++) s += (float)qv8[ch][e] * (float)kx[e];
        }
        Pt[j] = exp2f(s * EXP_C);
      }
    }
    __syncthreads();
    // phase 2: O[d] partials; group g covers ~145 keys, dim d contiguous in vtb
    {
      int d = t & 63, g = t >> 6;
      int j0 = g * 145, j1 = (g == 3) ? SEQ : (j0 + 145);
      const bf16_t* vrow = vbase + (size_t)d * SPAD;
      float o = 0.f;
      for (int j = j0; j < j1; j++) o += Pt[j] * (float)vrow[j];
      Ot[g * 64 + d] = o;
    }
    __syncthreads();
    if (wid == 0) {
      float l = 0.f;
      for (int k2 = lane; k2 < SEQ; k2 += 64) l += Pt[k2];
#pragma unroll
      for (int off = 1; off < 64; off <<= 1) l += __shfl_xor(l, off, 64);
      float sum = Ot[lane] + Ot[64 + lane] + Ot[128 + lane] + Ot[192 + lane];
      ao[((size_t)bb * SEQ + 576) * EMB + hh * HD + lane] = (bf16_t)(sum / l);
    }
  }
}

// ---------------- output projection, fp32 out (XCD-pinned n-columns) ----------------
// R9-proven: 2-phase dbuf + source-side XOR swizzle. Untouched this round.
__global__ __launch_bounds__(256) void k_oproj(const bf16_t* __restrict__ A,
                                               const bf16_t* __restrict__ Wo,
                                               const float* __restrict__ bo,
                                               float* __restrict__ out) {
  __shared__ __align__(16) bf16_t smem[2 * 8192];
  const int n0 = blockIdx.x * 128, m0 = blockIdx.y * 128;
  const int t = threadIdx.x;
  const int wid = t >> 6, lane = t & 63, quad = lane >> 4, c = lane & 15;
  const int wr = wid >> 1, wc = wid & 1;
  const int srow0 = t >> 2;                              // rows 0..63
  const int srow1 = 64 + srow0;                          // rows 64..127
  const int soff = (((t & 3) ^ ((t >> 3) & 3)) * 8);     // swizzled 16B slot (elems)

#define OPROJ_STAGE(buf, k0)                                                                 \
  {                                                                                          \
    bf16_t* As_ = smem + (buf) * 8192;                                                       \
    bf16_t* Bs_ = As_ + 4096;                                                                \
    GLOAD_LDS16(A + (size_t)(m0 + srow0) * EMB + (k0) + soff, (char*)As_ + (wid * 64) * 16); \
    GLOAD_LDS16(A + (size_t)(m0 + srow1) * EMB + (k0) + soff,                                \
                (char*)As_ + (256 + wid * 64) * 16);                                         \
    GLOAD_LDS16(Wo + (size_t)(n0 + srow0) * EMB + (k0) + soff, (char*)Bs_ + (wid * 64) * 16);\
    GLOAD_LDS16(Wo + (size_t)(n0 + srow1) * EMB + (k0) + soff,                               \
                (char*)Bs_ + (256 + wid * 64) * 16);                                         \
  }

  floatx4 acc[4][4];
#pragma unroll
  for (int i = 0; i < 4; i++)
#pragma unroll
    for (int j = 0; j < 4; j++) {
      floatx4 z = {0.f, 0.f, 0.f, 0.f};
      acc[i][j] = z;
    }

  OPROJ_STAGE(0, 0);
  __syncthreads();
  int cur = 0;
  for (int kt = 0; kt < 32; kt++) {
    if (kt < 31) OPROJ_STAGE(cur ^ 1, (kt + 1) * 32);
    const bf16_t* Asc = smem + cur * 8192;
    const bf16_t* Bsc = Asc + 4096;
    bf16x8 af[4], bfr[4];
#pragma unroll
    for (int mi = 0; mi < 4; mi++) {
      int row = wr * 64 + mi * 16 + c;
      af[mi] = *(const bf16x8*)(Asc + row * 32 + (quad * 8 ^ (((row >> 1) & 3) << 3)));
    }
#pragma unroll
    for (int ni = 0; ni < 4; ni++) {
      int row = wc * 64 + ni * 16 + c;
      bfr[ni] = *(const bf16x8*)(Bsc + row * 32 + (quad * 8 ^ (((row >> 1) & 3) << 3)));
    }
#pragma unroll
    for (int mi = 0; mi < 4; mi++)
#pragma unroll
      for (int ni = 0; ni < 4; ni++) acc[mi][ni] = MFMA16(af[mi], bfr[ni], acc[mi][ni]);
    __syncthreads();
    cur ^= 1;
  }
#undef OPROJ_STAGE

  float bias_v[4];
#pragma unroll
  for (int ni = 0; ni < 4; ni++) bias_v[ni] = bo[n0 + wc * 64 + ni * 16 + c];
#pragma unroll
  for (int mi = 0; mi < 4; mi++)
#pragma unroll
    for (int r = 0; r < 4; r++) {
      int m = m0 + wr * 64 + mi * 16 + quad * 4 + r;
      if (m >= MROWS) continue;
#pragma unroll
      for (int ni = 0; ni < 4; ni++)
        out[(size_t)m * EMB + n0 + wc * 64 + ni * 16 + c] = acc[mi][ni][r] + bias_v[ni];
    }
}

extern "C" void kernel_launch(void* const* d_in, const int* in_sizes, int n_in, void* d_out,
                              int out_size, void* d_ws, size_t ws_size, hipStream_t stream) {
  const float* hs = (const float*)d_in[0];
  const float* Wq = (const float*)d_in[1];
  const float* bq = (const float*)d_in[2];
  const float* Wk = (const float*)d_in[3];
  const float* bk = (const float*)d_in[4];
  const float* Wv = (const float*)d_in[5];
  const float* bv = (const float*)d_in[6];
  const float* Wo = (const float*)d_in[7];
  const float* bo = (const float*)d_in[8];
  float* out = (float*)d_out;
  char* ws = (char*)d_ws;

  bf16_t* hb = (bf16_t*)(ws + OFF_H);
  bf16_t* wqb = (bf16_t*)(ws + OFF_WQ);
  bf16_t* wkb = (bf16_t*)(ws + OFF_WK);
  bf16_t* wvb = (bf16_t*)(ws + OFF_WV);
  bf16_t* wob = (bf16_t*)(ws + OFF_WO);
  bf16_t* qbuf = (bf16_t*)(ws + OFF_Q);
  bf16_t* kbuf = (bf16_t*)(ws + OFF_K);
  bf16_t* vtbuf = (bf16_t*)(ws + OFF_VT);
  bf16_t* aob = (bf16_t*)(ws + OFF_AO);

  // no memset: pad reads are poison (stale bf16) and provably masked:
  // pad keys are never read (9 exact tiles + key-576 epilogue); 192-row q-tiles
  // cover rows 0..575 exactly; row 576 via the qt==2 VALU tail path.

  k_cast<<<13328, 256, 0, stream>>>((const float4*)hs, (const float4*)Wq, (const float4*)Wk,
                                    (const float4*)Wv, (const float4*)Wo, (bf16x4*)hb,
                                    (bf16x4*)wqb, (bf16x4*)wkb, (bf16x4*)wvb, (bf16x4*)wob);

  dim3 gq(16, 73);  // x = head/n-tile(64) -> XCD-pinned W; y = m-tile(128)
  k_qkv<<<gq, 256, 0, stream>>>(hb, wqb, wkb, wvb, bq, bk, bv, qbuf, kbuf, vtbuf);

  dim3 ga(16, 16, 3);  // x = head, y = batch, z = 192-row q-tile; 768 blocks @ 3/CU = one pass
  k_attn<<<ga, 256, 0, stream>>>(qbuf, kbuf, vtbuf, aob);

  dim3 go(8, 73);
  k_oproj<<<go, 256, 0, stream>>>(aob, wob, bo, out);
}

// Round 13
// 311.697 us; speedup vs baseline: 1.2942x; 1.2942x over previous
//
#include <hip/hip_runtime.h>
#include <hip/hip_bf16.h>
#include <stdint.h>

typedef __bf16 bf16_t;
typedef __attribute__((ext_vector_type(4))) float floatx4;
typedef __attribute__((ext_vector_type(8))) __bf16 bf16x8;
typedef __attribute__((ext_vector_type(4))) __bf16 bf16x4;

#define MFMA16(a, b, c) __builtin_amdgcn_mfma_f32_16x16x32_bf16(a, b, c, 0, 0, 0)

// async global->LDS, 16B per lane. LDS dest must be wave-uniform base (+lane*16 by HW).
#define GLOAD_LDS16(gsrc, ldst)                                                          \
  __builtin_amdgcn_global_load_lds((const __attribute__((address_space(1))) void*)(gsrc),\
                                   (__attribute__((address_space(3))) void*)(ldst),      \
                                   16, 0, 0)

#define BATCH 16
#define SEQ   577
#define EMB   1024
#define NH    16
#define HD    64
#define SPAD  640            // padded seq for attention buffers
#define MROWS (BATCH * SEQ)  // 9232
#define MPAD  9344           // 73 * 128

// exp(s/8) = 2^(s * log2(e)/8)
#define EXP_C 0.1803368801111404f

// ---------------- workspace layout (bytes) ----------------
#define OFF_H  0ULL                      // [MPAD][EMB] bf16      19,136,512
#define OFF_WQ 19136512ULL               // [EMB][EMB] bf16        2,097,152
#define OFF_WK 21233664ULL
#define OFF_WV 23330816ULL
#define OFF_WO 25427968ULL
#define OFF_Q  27525120ULL               // [B*H][SPAD][HD] bf16  20,971,520
#define OFF_K  48496640ULL
#define OFF_VT 69468160ULL               // [B*H][HD][SPAD] bf16 (transposed V)
#define OFF_AO 90439680ULL               // [MPAD][EMB] bf16      19,136,512

// ---------------- fp32 -> bf16 cast ----------------
__global__ __launch_bounds__(256) void k_cast(
    const float4* __restrict__ hs, const float4* __restrict__ wq,
    const float4* __restrict__ wk, const float4* __restrict__ wv,
    const float4* __restrict__ wo, bf16x4* __restrict__ hb, bf16x4* __restrict__ wqb,
    bf16x4* __restrict__ wkb, bf16x4* __restrict__ wvb, bf16x4* __restrict__ wob) {
  int idx = blockIdx.x * 256 + threadIdx.x;
  const int H4 = MROWS * EMB / 4;  // 2363392
  const int W4 = EMB * EMB / 4;    // 262144
  const float4* src;
  bf16x4* dst;
  int i;
  if (idx < H4) {
    src = hs; dst = hb; i = idx;
  } else {
    int r = idx - H4;
    int w = r / W4;
    if (w >= 4) return;
    i = r - w * W4;
    src = (w == 0) ? wq : (w == 1) ? wk : (w == 2) ? wv : wo;
    dst = (w == 0) ? wqb : (w == 1) ? wkb : (w == 2) ? wvb : wob;
  }
  float4 v = src[i];
  bf16x4 o;
  o.x = (bf16_t)v.x; o.y = (bf16_t)v.y; o.z = (bf16_t)v.z; o.w = (bf16_t)v.w;
  dst[i] = o;
}

// ---------------- fused QKV projection + RoPE (z-fused, n-tile=64=one head)
// R9-proven: 2-phase dbuf + source-side XOR swizzle (8-way -> 2-way on
// ds_read_b128). Untouched this round.
__global__ __launch_bounds__(256, 3) void k_qkv(const bf16_t* __restrict__ A,
                                                const bf16_t* __restrict__ Wq,
                                                const bf16_t* __restrict__ Wk,
                                                const bf16_t* __restrict__ Wv,
                                                const float* __restrict__ bq,
                                                const float* __restrict__ bk,
                                                const float* __restrict__ bv,
                                                bf16_t* __restrict__ qb,
                                                bf16_t* __restrict__ kb,
                                                bf16_t* __restrict__ vtb) {
  // per buffer: As 128x32 (4096 el) | Bs 3x64x32 (6144 el) = 20480 B; x2 = 40960 B -> 4 blocks/CU
  __shared__ __align__(16) bf16_t smem[2 * 10240];
  const int hh = blockIdx.x;           // head == n-tile
  const int n0 = hh * 64;
  const int m0 = blockIdx.y * 128;
  const int t = threadIdx.x;
  const int wid = t >> 6, lane = t & 63, quad = lane >> 4, c = lane & 15;

  // staging: row = t>>2; source slot XOR-swizzled so linear LDS dest ends up
  // holding LDS[row][slot] = G[row][slot ^ ((row>>1)&3)]
  const int srow0 = t >> 2;                              // rows 0..63
  const int srow1 = 64 + srow0;                          // rows 64..127
  const int soff = (((t & 3) ^ ((t >> 3) & 3)) * 8);     // swizzled 16B slot (elems)

#define QKV_STAGE(buf, k0)                                                                  \
  {                                                                                         \
    bf16_t* As_ = smem + (buf) * 10240;                                                     \
    bf16_t* Bs_ = As_ + 4096;                                                               \
    GLOAD_LDS16(A + (size_t)(m0 + srow0) * EMB + (k0) + soff, (char*)As_ + (wid * 64) * 16);\
    GLOAD_LDS16(A + (size_t)(m0 + srow1) * EMB + (k0) + soff,                               \
                (char*)As_ + (256 + wid * 64) * 16);                                        \
    GLOAD_LDS16(Wq + (size_t)(n0 + srow0) * EMB + (k0) + soff, (char*)Bs_ + (wid * 64) * 16);\
    GLOAD_LDS16(Wk + (size_t)(n0 + srow0) * EMB + (k0) + soff,                              \
                (char*)Bs_ + 4096 + (wid * 64) * 16);                                       \
    GLOAD_LDS16(Wv + (size_t)(n0 + srow0) * EMB + (k0) + soff,                              \
                (char*)Bs_ + 8192 + (wid * 64) * 16);                                       \
  }

  floatx4 acc[3][2][4];
#pragma unroll
  for (int z = 0; z < 3; z++)
#pragma unroll
    for (int i = 0; i < 2; i++)
#pragma unroll
      for (int j = 0; j < 4; j++) {
        floatx4 zz = {0.f, 0.f, 0.f, 0.f};
        acc[z][i][j] = zz;
      }

  QKV_STAGE(0, 0);
  __syncthreads();  // buf0 staged (compiler drains vmcnt here)
  int cur = 0;
  for (int kt = 0; kt < 32; kt++) {
    if (kt < 31) QKV_STAGE(cur ^ 1, (kt + 1) * 32);  // async; flies under compute below
    const bf16_t* Asc = smem + cur * 10240;
    const bf16_t* Bsc = Asc + 4096;
    bf16x8 af[2];
#pragma unroll
    for (int mi = 0; mi < 2; mi++) {
      int row = wid * 32 + mi * 16 + c;
      af[mi] = *(const bf16x8*)(Asc + row * 32 + (quad * 8 ^ (((row >> 1) & 3) << 3)));
    }
#pragma unroll
    for (int z = 0; z < 3; z++) {
      bf16x8 bfr[4];
#pragma unroll
      for (int ni = 0; ni < 4; ni++) {
        int row = ni * 16 + c;
        bfr[ni] = *(const bf16x8*)(Bsc + z * 2048 + row * 32 + (quad * 8 ^ (((row >> 1) & 3) << 3)));
      }
#pragma unroll
      for (int mi = 0; mi < 2; mi++)
#pragma unroll
        for (int ni = 0; ni < 4; ni++) acc[z][mi][ni] = MFMA16(af[mi], bfr[ni], acc[z][mi][ni]);
    }
    __syncthreads();  // drains next-tile loads (already covered) + read-done for buf[cur]
    cur ^= 1;
  }
#undef QKV_STAGE

  // inv_freq[c] = 10000^(-c/16) = 2^(-c*log2(10000)/16)
  const float invf = exp2f(-(float)c * 0.8304820237218405f);

  for (int z = 0; z < 3; z++) {
    const float* bias = (z == 0) ? bq : (z == 1) ? bk : bv;
    float bias_v[4];
#pragma unroll
    for (int ni = 0; ni < 4; ni++) bias_v[ni] = bias[n0 + ni * 16 + c];
#pragma unroll
    for (int mi = 0; mi < 2; mi++) {
#pragma unroll
      for (int r = 0; r < 4; r++) {
        int m = m0 + wid * 32 + mi * 16 + quad * 4 + r;
        if (m >= MROWS) continue;
        int bb = m / SEQ;
        int s = m - bb * SEQ;
        if (z < 2) {
          float ch = 1.f, sh = 0.f, cw = 1.f, sw = 0.f;
          if (s > 0) {
            int p = s - 1;
            int hp = p / 24, wp2 = p - (p / 24) * 24;
            __sincosf((float)hp * invf, &sh, &ch);
            __sincosf((float)wp2 * invf, &sw, &cw);
          }
          bf16_t* dst = (z == 0) ? qb : kb;
          size_t rowoff = ((size_t)(bb * NH + hh) * SPAD + s) * HD;
#pragma unroll
          for (int ni = 0; ni < 4; ni++) {
            float val = acc[z][mi][ni][r] + bias_v[ni];
            float part = acc[z][mi][ni ^ 2][r] + bias_v[ni ^ 2];
            float rot = (ni < 2) ? -part : part;
            float cs = (ni < 2) ? ch : cw;
            float sn = (ni < 2) ? sh : sw;
            dst[rowoff + ni * 16 + c] = (bf16_t)(val * cs + rot * sn);
          }
        } else {
          size_t base = (size_t)(bb * NH + hh) * HD;
#pragma unroll
          for (int ni = 0; ni < 4; ni++) {
            float val = acc[z][mi][ni][r] + bias_v[ni];
            int d = ni * 16 + c;
            vtb[(base + d) * SPAD + s] = (bf16_t)val;  // transposed store [d][s]
          }
        }
      }
    }
  }
}

// ---------------- flash attention ----------------
// R13: REVERT to R10-exact inner loop (best measured: 96.4 us / 312.8 total).
// R12 LESSON (measured): K/V dbuf's 46080 B request allocates as 54272 B
// (same +8KB inflation as R3) -> 2 blocks/CU cliff -> 183 us. The LDS route
// to single-barrier is closed; barrier theory remains untested.
// R13 delta: s_setprio(1)/(0) around the MFMA clusters (T5). Prerequisite is
// wave phase-diversity on the CU -- satisfied here by 3 independent blocks
// (m191: +4-7% on attn in this regime; m190's null was single-block lockstep).
// Zero register/LDS/correctness footprint.
#define PSTR 72  // P round-trip stride: breaks 128B bank aliasing
#define OSTR 66  // O-transpose stride
#define MI   3   // m-tiles per wave (48 rows)
__global__ __launch_bounds__(256, 3) void k_attn(const bf16_t* __restrict__ qb,
                                                 const bf16_t* __restrict__ kb,
                                                 const bf16_t* __restrict__ vtb,
                                                 bf16_t* __restrict__ ao) {
  __shared__ __align__(16) bf16_t smem[13824];  // 27648 B total (R9-measured exact)
  bf16_t* Ks = smem;            // 64*72 = 4608 elems
  bf16_t* Vs = smem + 4608;     // 64*72, [d][key]
  bf16_t* Ps = smem + 9216;     // 4 waves * 1152 elems (P: 16 rows*72; O: 16 rows*66)
  const int t = threadIdx.x, wid = t >> 6, lane = t & 63, quad = lane >> 4, c = lane & 15;
  const int hh = blockIdx.x, bb = blockIdx.y, qt = blockIdx.z;
  const size_t bh = (size_t)bb * NH + hh;
  const bf16_t* qall = qb + bh * SPAD * HD;
  const bf16_t* qbase = qall + (size_t)qt * 192 * HD;
  const bf16_t* kbase = kb + bh * SPAD * HD;
  const bf16_t* vbase = vtb + bh * HD * SPAD;
  bf16_t* Pw = Ps + wid * 1152;

  // Q fragments direct from global. Max row = 2*192 + 3*48 + 2*16 + 15 = 575:
  // all reads valid, no pad/poison exposure on the Q side.
  bf16x8 aq[MI][2];
#pragma unroll
  for (int mi = 0; mi < MI; mi++)
#pragma unroll
    for (int h = 0; h < 2; h++)
      aq[mi][h] = *(const bf16x8*)(qbase + (size_t)(wid * 48 + mi * 16 + c) * HD + h * 32 + quad * 8);

  // prefetch K/V tile kt=0 into regs
  uint4 kr[2], vr[2];
#pragma unroll
  for (int j = 0; j < 2; j++) {
    int ci = j * 256 + t;
    int row = ci >> 3, off = (ci & 7) * 8;
    kr[j] = *(const uint4*)(kbase + (size_t)row * HD + off);
    vr[j] = *(const uint4*)(vbase + (size_t)row * SPAD + off);
  }

  floatx4 acc_o[MI][4];
  float lsum[MI][4];
#pragma unroll
  for (int mi = 0; mi < MI; mi++) {
    floatx4 z = {0.f, 0.f, 0.f, 0.f};
#pragma unroll
    for (int nd = 0; nd < 4; nd++) acc_o[mi][nd] = z;
#pragma unroll
    for (int r = 0; r < 4; r++) lsum[mi][r] = 0.f;
  }

  for (int kt = 0; kt < 9; kt++) {  // 9*64 = 576 keys exactly; key 576 in epilogue
    __syncthreads();  // all waves done reading prev Ks/Vs; prefetch already landed
#pragma unroll
    for (int j = 0; j < 2; j++) {
      int ci = j * 256 + t;
      int row = ci >> 3, off = (ci & 7) * 8;
      *(uint4*)((char*)Ks + (row * PSTR + off) * 2) = kr[j];
      *(uint4*)((char*)Vs + (row * PSTR + off) * 2) = vr[j];
    }
    __syncthreads();  // staging visible
    if (kt < 8) {     // prefetch next tile; overlaps the compute below
#pragma unroll
      for (int j = 0; j < 2; j++) {
        int ci = j * 256 + t;
        int row = ci >> 3, off = (ci & 7) * 8;
        kr[j] = *(const uint4*)(kbase + (size_t)((kt + 1) * 64 + row) * HD + off);
        vr[j] = *(const uint4*)(vbase + (size_t)row * SPAD + (kt + 1) * 64 + off);
      }
    }

    // QK^T: 24 MFMA (K fragments shared across all 3 mi)
    floatx4 sc[MI][4];
    __builtin_amdgcn_s_setprio(1);
#pragma unroll
    for (int ni = 0; ni < 4; ni++) {
      bf16x8 k0 = *(const bf16x8*)(Ks + (ni * 16 + c) * PSTR + quad * 8);
      bf16x8 k1 = *(const bf16x8*)(Ks + (ni * 16 + c) * PSTR + 32 + quad * 8);
#pragma unroll
      for (int mi = 0; mi < MI; mi++) {
        floatx4 zz = {0.f, 0.f, 0.f, 0.f};
        zz = MFMA16(aq[mi][0], k0, zz);
        zz = MFMA16(aq[mi][1], k1, zz);
        sc[mi][ni] = zz;
      }
    }
    __builtin_amdgcn_s_setprio(0);

    // per-mi: p = exp(s/8) -> 16-row LDS region (C-layout -> A-layout) -> PV.
    // 16-row Pw reused across mi (same-wave DS ordering); l as scalar partials.
#pragma unroll
    for (int mi = 0; mi < MI; mi++) {
#pragma unroll
      for (int ni = 0; ni < 4; ni++)
#pragma unroll
        for (int r = 0; r < 4; r++) {
          float p = exp2f(sc[mi][ni][r] * EXP_C);
          lsum[mi][r] += p;
          Pw[(quad * 4 + r) * PSTR + ni * 16 + c] = (bf16_t)p;
        }
      // same-wave LDS round trip: no barrier needed
      bf16x8 pa0 = *(const bf16x8*)(Pw + c * PSTR + quad * 8);
      bf16x8 pa1 = *(const bf16x8*)(Pw + c * PSTR + 32 + quad * 8);
      // PV: 8 MFMA
      __builtin_amdgcn_s_setprio(1);
#pragma unroll
      for (int nd = 0; nd < 4; nd++) {
        bf16x8 v0 = *(const bf16x8*)(Vs + (nd * 16 + c) * PSTR + quad * 8);
        bf16x8 v1 = *(const bf16x8*)(Vs + (nd * 16 + c) * PSTR + 32 + quad * 8);
        acc_o[mi][nd] = MFMA16(pa0, v0, acc_o[mi][nd]);
        acc_o[mi][nd] = MFMA16(pa1, v1, acc_o[mi][nd]);
      }
      __builtin_amdgcn_s_setprio(0);
    }
  }

  // ---- epilogue: key 576 for query rows 0..575 ----
  {
    bf16x8 klast[2];
#pragma unroll
    for (int h = 0; h < 2; h++) {
      bf16x8 kk;
#pragma unroll
      for (int i = 0; i < 8; i++) kk[i] = (bf16_t)0.0f;
      if (c == 0) kk = *(const bf16x8*)(kbase + (size_t)576 * HD + h * 32 + quad * 8);
      klast[h] = kk;
    }
    float vlast[4];
#pragma unroll
    for (int nd = 0; nd < 4; nd++)
      vlast[nd] = (float)vbase[(size_t)(nd * 16 + c) * SPAD + 576];
#pragma unroll
    for (int mi = 0; mi < MI; mi++) {
      floatx4 zz = {0.f, 0.f, 0.f, 0.f};
      zz = MFMA16(aq[mi][0], klast[0], zz);
      zz = MFMA16(aq[mi][1], klast[1], zz);  // D col 0 (lanes c==0) = scores
#pragma unroll
      for (int r = 0; r < 4; r++) {
        float p = exp2f(zz[r] * EXP_C);
        p = __shfl(p, quad * 16, 64);  // broadcast score row from this quad's c==0 lane
#pragma unroll
        for (int nd = 0; nd < 4; nd++) acc_o[mi][nd][r] += p * vlast[nd];
        if (c == 0) lsum[mi][r] += p;  // count once per row (partials reduce over c later)
      }
    }
  }

  // ---- row-sum finalize: reduce per-lane partials over the 16 c-lanes ----
#pragma unroll
  for (int mi = 0; mi < MI; mi++)
#pragma unroll
    for (int r = 0; r < 4; r++) {
      float l = lsum[mi][r];
      l += __shfl_xor(l, 1, 64);
      l += __shfl_xor(l, 2, 64);
      l += __shfl_xor(l, 4, 64);
      l += __shfl_xor(l, 8, 64);
      lsum[mi][r] = l;  // all lanes in the quad-group now hold the row sum
    }

  // ---- coalesced O-store: per-mi 16-row transpose chunks through Pw (dead now),
  // then full 128B-row dwordx4 stores. Same-wave DS ordering: no barrier.
  {
    const int rsub = lane >> 3, c8 = lane & 7;  // 8 rows/instr, 16B per lane
#pragma unroll
    for (int mi = 0; mi < MI; mi++) {
#pragma unroll
      for (int r = 0; r < 4; r++) {
        float inv_l = 1.f / lsum[mi][r];
        int row = quad * 4 + r;  // row within this 16-row chunk
#pragma unroll
        for (int nd = 0; nd < 4; nd++)
          Pw[row * OSTR + nd * 16 + c] = (bf16_t)(acc_o[mi][nd][r] * inv_l);
      }
#pragma unroll
      for (int j = 0; j < 2; j++) {
        int row = j * 8 + rsub;  // 0..15 within chunk
        bf16x8 ov = *(const bf16x8*)(Pw + row * OSTR + c8 * 8);
        int q = qt * 192 + wid * 48 + mi * 16 + row;  // <= 575, always valid
        if (q < SEQ) {
          size_t mrow = (size_t)bb * SEQ + q;
          *(bf16x8*)(ao + mrow * EMB + hh * HD + c8 * 8) = ov;
        }
      }
    }
  }

  // ---- tail: query row 576 (VALU path, qt==2 blocks only; K/V are L2-hot) ----
  if (qt == 2) {
    float* Pt = (float*)Ks;            // 577 floats (2.3 KB) in dead Ks region
    float* Ot = Pt + 584;              // 4*64 floats
    __syncthreads();                   // all waves past their last Ks reads
    // phase 1: scores for keys j = t, t+256, t+512
    bf16x8 qv8[8];
    const bf16_t* q576 = qall + (size_t)576 * HD;
#pragma unroll
    for (int ch = 0; ch < 8; ch++) qv8[ch] = *(const bf16x8*)(q576 + ch * 8);
#pragma unroll
    for (int rep = 0; rep < 3; rep++) {
      int j = t + rep * 256;
      if (j < SEQ) {
        const bf16_t* krow = kbase + (size_t)j * HD;
        float s = 0.f;
#pragma unroll
        for (int ch = 0; ch < 8; ch++) {
          bf16x8 kx = *(const bf16x8*)(krow + ch * 8);
#pragma unroll
          for (int e = 0; e < 8; e++) s += (float)qv8[ch][e] * (float)kx[e];
        }
        Pt[j] = exp2f(s * EXP_C);
      }
    }
    __syncthreads();
    // phase 2: O[d] partials; group g covers ~145 keys, dim d contiguous in vtb
    {
      int d = t & 63, g = t >> 6;
      int j0 = g * 145, j1 = (g == 3) ? SEQ : (j0 + 145);
      const bf16_t* vrow = vbase + (size_t)d * SPAD;
      float o = 0.f;
      for (int j = j0; j < j1; j++) o += Pt[j] * (float)vrow[j];
      Ot[g * 64 + d] = o;
    }
    __syncthreads();
    if (wid == 0) {
      float l = 0.f;
      for (int k2 = lane; k2 < SEQ; k2 += 64) l += Pt[k2];
#pragma unroll
      for (int off = 1; off < 64; off <<= 1) l += __shfl_xor(l, off, 64);
      float sum = Ot[lane] + Ot[64 + lane] + Ot[128 + lane] + Ot[192 + lane];
      ao[((size_t)bb * SEQ + 576) * EMB + hh * HD + lane] = (bf16_t)(sum / l);
    }
  }
}

// ---------------- output projection, fp32 out (XCD-pinned n-columns) ----------------
// R9-proven: 2-phase dbuf + source-side XOR swizzle. Untouched this round.
__global__ __launch_bounds__(256) void k_oproj(const bf16_t* __restrict__ A,
                                               const bf16_t* __restrict__ Wo,
                                               const float* __restrict__ bo,
                                               float* __restrict__ out) {
  __shared__ __align__(16) bf16_t smem[2 * 8192];
  const int n0 = blockIdx.x * 128, m0 = blockIdx.y * 128;
  const int t = threadIdx.x;
  const int wid = t >> 6, lane = t & 63, quad = lane >> 4, c = lane & 15;
  const int wr = wid >> 1, wc = wid & 1;
  const int srow0 = t >> 2;                              // rows 0..63
  const int srow1 = 64 + srow0;                          // rows 64..127
  const int soff = (((t & 3) ^ ((t >> 3) & 3)) * 8);     // swizzled 16B slot (elems)

#define OPROJ_STAGE(buf, k0)                                                                 \
  {                                                                                          \
    bf16_t* As_ = smem + (buf) * 8192;                                                       \
    bf16_t* Bs_ = As_ + 4096;                                                                \
    GLOAD_LDS16(A + (size_t)(m0 + srow0) * EMB + (k0) + soff, (char*)As_ + (wid * 64) * 16); \
    GLOAD_LDS16(A + (size_t)(m0 + srow1) * EMB + (k0) + soff,                                \
                (char*)As_ + (256 + wid * 64) * 16);                                         \
    GLOAD_LDS16(Wo + (size_t)(n0 + srow0) * EMB + (k0) + soff, (char*)Bs_ + (wid * 64) * 16);\
    GLOAD_LDS16(Wo + (size_t)(n0 + srow1) * EMB + (k0) + soff,                               \
                (char*)Bs_ + (256 + wid * 64) * 16);                                         \
  }

  floatx4 acc[4][4];
#pragma unroll
  for (int i = 0; i < 4; i++)
#pragma unroll
    for (int j = 0; j < 4; j++) {
      floatx4 z = {0.f, 0.f, 0.f, 0.f};
      acc[i][j] = z;
    }

  OPROJ_STAGE(0, 0);
  __syncthreads();
  int cur = 0;
  for (int kt = 0; kt < 32; kt++) {
    if (kt < 31) OPROJ_STAGE(cur ^ 1, (kt + 1) * 32);
    const bf16_t* Asc = smem + cur * 8192;
    const bf16_t* Bsc = Asc + 4096;
    bf16x8 af[4], bfr[4];
#pragma unroll
    for (int mi = 0; mi < 4; mi++) {
      int row = wr * 64 + mi * 16 + c;
      af[mi] = *(const bf16x8*)(Asc + row * 32 + (quad * 8 ^ (((row >> 1) & 3) << 3)));
    }
#pragma unroll
    for (int ni = 0; ni < 4; ni++) {
      int row = wc * 64 + ni * 16 + c;
      bfr[ni] = *(const bf16x8*)(Bsc + row * 32 + (quad * 8 ^ (((row >> 1) & 3) << 3)));
    }
#pragma unroll
    for (int mi = 0; mi < 4; mi++)
#pragma unroll
      for (int ni = 0; ni < 4; ni++) acc[mi][ni] = MFMA16(af[mi], bfr[ni], acc[mi][ni]);
    __syncthreads();
    cur ^= 1;
  }
#undef OPROJ_STAGE

  float bias_v[4];
#pragma unroll
  for (int ni = 0; ni < 4; ni++) bias_v[ni] = bo[n0 + wc * 64 + ni * 16 + c];
#pragma unroll
  for (int mi = 0; mi < 4; mi++)
#pragma unroll
    for (int r = 0; r < 4; r++) {
      int m = m0 + wr * 64 + mi * 16 + quad * 4 + r;
      if (m >= MROWS) continue;
#pragma unroll
      for (int ni = 0; ni < 4; ni++)
        out[(size_t)m * EMB + n0 + wc * 64 + ni * 16 + c] = acc[mi][ni][r] + bias_v[ni];
    }
}

extern "C" void kernel_launch(void* const* d_in, const int* in_sizes, int n_in, void* d_out,
                              int out_size, void* d_ws, size_t ws_size, hipStream_t stream) {
  const float* hs = (const float*)d_in[0];
  const float* Wq = (const float*)d_in[1];
  const float* bq = (const float*)d_in[2];
  const float* Wk = (const float*)d_in[3];
  const float* bk = (const float*)d_in[4];
  const float* Wv = (const float*)d_in[5];
  const float* bv = (const float*)d_in[6];
  const float* Wo = (const float*)d_in[7];
  const float* bo = (const float*)d_in[8];
  float* out = (float*)d_out;
  char* ws = (char*)d_ws;

  bf16_t* hb = (bf16_t*)(ws + OFF_H);
  bf16_t* wqb = (bf16_t*)(ws + OFF_WQ);
  bf16_t* wkb = (bf16_t*)(ws + OFF_WK);
  bf16_t* wvb = (bf16_t*)(ws + OFF_WV);
  bf16_t* wob = (bf16_t*)(ws + OFF_WO);
  bf16_t* qbuf = (bf16_t*)(ws + OFF_Q);
  bf16_t* kbuf = (bf16_t*)(ws + OFF_K);
  bf16_t* vtbuf = (bf16_t*)(ws + OFF_VT);
  bf16_t* aob = (bf16_t*)(ws + OFF_AO);

  // no memset: pad reads are poison (stale bf16) and provably masked:
  // pad keys are never read (9 exact tiles + key-576 epilogue); 192-row q-tiles
  // cover rows 0..575 exactly; row 576 via the qt==2 VALU tail path.

  k_cast<<<13328, 256, 0, stream>>>((const float4*)hs, (const float4*)Wq, (const float4*)Wk,
                                    (const float4*)Wv, (const float4*)Wo, (bf16x4*)hb,
                                    (bf16x4*)wqb, (bf16x4*)wkb, (bf16x4*)wvb, (bf16x4*)wob);

  dim3 gq(16, 73);  // x = head/n-tile(64) -> XCD-pinned W; y = m-tile(128)
  k_qkv<<<gq, 256, 0, stream>>>(hb, wqb, wkb, wvb, bq, bk, bv, qbuf, kbuf, vtbuf);

  dim3 ga(16, 16, 3);  // x = head, y = batch, z = 192-row q-tile; 768 blocks @ 3/CU = one pass
  k_attn<<<ga, 256, 0, stream>>>(qbuf, kbuf, vtbuf, aob);

  dim3 go(8, 73);
  k_oproj<<<go, 256, 0, stream>>>(aob, wob, bo, out);
}